// Round 2
// baseline (552.364 us; speedup 1.0000x reference)
//
#include <hip/hip_runtime.h>
#include <stdint.h>
#include <stddef.h>

typedef float    f32x4  __attribute__((ext_vector_type(4)));
typedef short    bf16x8 __attribute__((ext_vector_type(8)));
typedef uint16_t u16x8  __attribute__((ext_vector_type(8)));
typedef uint32_t u32x4  __attribute__((ext_vector_type(4)));

#define ATT_ROW 136   // 128 data + 8 zero pad (=> 272B rows, 16B aligned)

// ---------- helpers ----------
__device__ __forceinline__ uint16_t f2bf(float x) {
  union { float f; uint32_t u; } c; c.f = x;
  return (uint16_t)((c.u + 0x7FFFu + ((c.u >> 16) & 1u)) >> 16);  // RNE
}
__device__ __forceinline__ float bf2f(uint16_t h) {
  union { uint32_t u; float f; } c; c.u = ((uint32_t)h) << 16;
  return c.f;
}
// XOR swizzle for 64B-row LDS tiles: byte a -> a ^ ((row-bits)<<4). Bijective
// (not involutive); used consistently on write+read, with explicit inverse in k_prep.
__device__ __forceinline__ int S64s(int a) { return a ^ (((a >> 6) & 7) << 4); }

__device__ __forceinline__ void cp16(void* lds, const void* g) {
  __builtin_amdgcn_global_load_lds((const __attribute__((address_space(1))) void*)g,
                                   (__attribute__((address_space(3))) void*)lds, 16, 0, 0);
}
__device__ __forceinline__ float fast_tanh(float t) {
  float r = __expf(-2.f * t);
  return 1.f - 2.f * r / (1.f + r);
}

// ---------- prep: fc1_W (fp32 [65536][256]) -> bf16 chunked column-major, swizzled ----------
// chunk c (32 k-rows): 16B unit for (n,g) lives at byte S64s(n*64+g*16), holding
// W[c*32 + g*8 + e][n], e=0..7 (k-contiguous bf16)
__global__ __launch_bounds__(256) void k_prep(const float* __restrict__ W1,
                                              uint16_t* __restrict__ W1s) {
  __shared__ float st[32 * 256];
  const int c = blockIdx.x, tid = threadIdx.x;
  const float* src = W1 + (size_t)c * 32 * 256;
#pragma unroll
  for (int it = 0; it < 8; ++it) {
    int u = it * 256 + tid;
    ((f32x4*)st)[u] = ((const f32x4*)src)[u];
  }
  __syncthreads();
  uint16_t* dstc = W1s + (size_t)c * 8192;
#pragma unroll
  for (int q = 0; q < 4; ++q) {
    int p  = q * 256 + tid;       // 16B unit 0..1023
    int Np = p >> 2, Gp = p & 3;
    int n  = Np ^ ((Np >> 2) & 1);   // invert S64
    int g  = Gp ^ (n & 3);
    uint32_t w[4];
#pragma unroll
    for (int e2 = 0; e2 < 4; ++e2) {
      uint16_t lo = f2bf(st[(g * 8 + 2 * e2) * 256 + n]);
      uint16_t hi = f2bf(st[(g * 8 + 2 * e2 + 1) * 256 + n]);
      w[e2] = (uint32_t)lo | ((uint32_t)hi << 16);
    }
    u32x4 v; v.x = w[0]; v.y = w[1]; v.z = w[2]; v.w = w[3];
    *(u32x4*)(dstc + (size_t)p * 8) = v;
  }
}

// ---------- attention: per-b softmax attention, writes bf16 att slab [B][9][136] ----------
__global__ __launch_bounds__(512) void k_att(const float* __restrict__ X,
    const float* __restrict__ aW, const float* __restrict__ aU,
    const float* __restrict__ aV, uint16_t* __restrict__ att) {
  __shared__ float sa[8][8][66];
  __shared__ float su[8][8][66];
  __shared__ float sal[8][64];
  __shared__ float sv[64];
  const int tid = threadIdx.x, lane = tid & 63, w = tid >> 6;
  if (tid < 64) sv[tid] = aV[tid];
  __syncthreads();
  for (int rep = 0; rep < 2; ++rep) {
    int b  = blockIdx.x * 16 + w * 2 + rep;
    int bu = __builtin_amdgcn_readfirstlane(b);
    const float* xb = X + (size_t)bu * 512;
    float xi[8];
#pragma unroll
    for (int i = 0; i < 8; ++i) xi[i] = xb[i * 64 + lane];
    float a[8], u[8];
#pragma unroll
    for (int i = 0; i < 8; ++i) { a[i] = 0.f; u[i] = 0.f; }
#pragma unroll
    for (int f = 0; f < 64; ++f) {
      float wf = aW[f * 64 + lane];
      float uf = aU[f * 64 + lane];
#pragma unroll
      for (int i = 0; i < 8; ++i) {
        float xs = xb[i * 64 + f];      // wave-uniform -> s_load
        a[i] = fmaf(xs, wf, a[i]);
        u[i] = fmaf(xs, uf, u[i]);
      }
    }
#pragma unroll
    for (int i = 0; i < 8; ++i) { sa[w][i][lane] = a[i]; su[w][i][lane] = u[i]; }
    __syncthreads();
    // e + softmax: lane -> (i2,j2)
    int i2 = lane >> 3, j2 = lane & 7;
    float ev = 0.f;
#pragma unroll
    for (int h = 0; h < 64; ++h)
      ev = fmaf(fast_tanh(sa[w][i2][h] + su[w][j2][h]), sv[h], ev);
    float m = ev;
    m = fmaxf(m, __shfl_xor(m, 1));
    m = fmaxf(m, __shfl_xor(m, 2));
    m = fmaxf(m, __shfl_xor(m, 4));
    float p = __expf(ev - m);
    float s = p;
    s += __shfl_xor(s, 1); s += __shfl_xor(s, 2); s += __shfl_xor(s, 4);
    sal[w][lane] = p / s;
    __syncthreads();
    // ctx + store (lane plays f role)
#pragma unroll
    for (int i = 0; i < 8; ++i) {
      float c = 0.f;
#pragma unroll
      for (int j = 0; j < 8; ++j) c = fmaf(sal[w][i * 8 + j], xi[j], c);
      c = fmaf(-sal[w][i * 8 + i], xi[i], c);
      size_t ro = ((size_t)b * 9 + i) * ATT_ROW;
      att[ro + lane]      = f2bf(xi[i]);
      att[ro + 64 + lane] = f2bf(c);
      if (lane < 8) att[ro + 128 + lane] = 0;
    }
    { // zero row 8 (SAME-padding bottom row)
      size_t ro = ((size_t)b * 9 + 8) * ATT_ROW;
      att[ro + lane] = 0; att[ro + 64 + lane] = 0;
      if (lane < 8) att[ro + 128 + lane] = 0;
    }
    __syncthreads();
  }
}

// ---------- graph path ----------
__global__ void k_deg(const int* __restrict__ src, const int* __restrict__ dst,
                      float* degO, float* degI) {
  int t = blockIdx.x * 256 + threadIdx.x;
  if (t < 4096) {
    atomicAdd(degO + src[t], 1.f);
    atomicAdd(degI + dst[t], 1.f);
  }
}
__global__ __launch_bounds__(256) void k_gca(const float* __restrict__ h,
    const int* __restrict__ src, const int* __restrict__ dst,
    const float* __restrict__ degO, float* __restrict__ agg) {
  int t = blockIdx.x * 256 + threadIdx.x;   // 4096*128
  int e = t >> 7, d = t & 127;
  int s = src[e];
  float sc = rsqrtf(fmaxf(degO[s], 1.f));
  atomicAdd(agg + (size_t)dst[e] * 128 + d, h[(size_t)s * 128 + d] * sc);
}
__global__ __launch_bounds__(128) void k_gc1b(const float* __restrict__ agg,
    const float* __restrict__ degI, const float* __restrict__ Wt,
    const float* __restrict__ bs, float* __restrict__ h1) {
  __shared__ float vs[128];
  int n = blockIdx.x, t = threadIdx.x;
  float sc = rsqrtf(fmaxf(degI[n], 1.f));
  vs[t] = agg[(size_t)n * 128 + t] * sc;
  __syncthreads();
  float acc = bs[t];
#pragma unroll 8
  for (int d = 0; d < 128; ++d) acc = fmaf(vs[d], Wt[d * 128 + t], acc);
  h1[(size_t)n * 128 + t] = fmaxf(acc, 0.f);
}
__global__ __launch_bounds__(128) void k_gc2b(const float* __restrict__ agg,
    const float* __restrict__ degI, const float* __restrict__ Wt,
    const float* __restrict__ bs, float* __restrict__ h2) {
  __shared__ float vs[128];
  int n = blockIdx.x, t = threadIdx.x;
  float sc = rsqrtf(fmaxf(degI[n], 1.f));
  vs[t] = agg[(size_t)n * 128 + t] * sc;
  __syncthreads();
  if (t < 8) {
    float acc = bs[t];
#pragma unroll 8
    for (int d = 0; d < 128; ++d) acc = fmaf(vs[d], Wt[d * 8 + t], acc);
    h2[(size_t)n * 8 + t] = acc;   // no relu
  }
}
__global__ __launch_bounds__(128) void k_e12(const float* __restrict__ ef,
    const float* __restrict__ W1, const float* __restrict__ b1,
    const float* __restrict__ W2, const float* __restrict__ b2,
    float* __restrict__ e2) {
  __shared__ float efs[128];
  __shared__ float t1s[128];
  int t = threadIdx.x;
  for (int it = 0; it < 16; ++it) {
    int b = blockIdx.x * 16 + it;
    efs[t] = ef[(size_t)b * 128 + t];
    __syncthreads();
    float acc = b1[t];
#pragma unroll 8
    for (int d = 0; d < 128; ++d) acc = fmaf(efs[d], W1[d * 128 + t], acc);
    t1s[t] = fmaxf(acc, 0.f);
    __syncthreads();
    if (t < 8) {
      float a2 = b2[t];
#pragma unroll 8
      for (int h = 0; h < 128; ++h) a2 = fmaf(t1s[h], W2[h * 8 + t], a2);
      e2[(size_t)b * 8 + t] = fmaxf(a2, 0.f);
    }
    __syncthreads();
  }
}

// ---------- fused conv + fc1 GEMM ----------
// grid 256: bid -> i=bid&7 (XCD-pinned), oh=(bid>>3)&1, btile=bid>>4
// block 512 thr = 8 waves (2M x 4N), BM=256, BN=256, BK=32, split-K atomicAdd into out1
struct Win { u16x8 a0, a1, b0, b1; uint16_t ae, be; };

__global__ __launch_bounds__(512) void k_gemm(const uint16_t* __restrict__ W1s,
    const uint16_t* __restrict__ att, const float* __restrict__ conv_w,
    const float* __restrict__ conv_b, float* __restrict__ out1) {
  __shared__ __align__(16) char smem[65536];
  char* Abuf = smem;            // [2][16384]  A-tile [256m][32k] bf16, S64-swizzled
  char* Bbuf = smem + 32768;    // [2][16384]  W chunk, pre-swizzled in global

  const int tid = threadIdx.x;
  const int lane = tid & 63, ln15 = lane & 15, g = lane >> 4;
  const int wid = tid >> 6, wm = wid >> 2, wn = wid & 3;
  const int bid = blockIdx.x;
  const int i_row = bid & 7, oh = (bid >> 3) & 1, btile = bid >> 4;
  const int b0 = btile * 256;
  const int am = tid >> 1, ag = tid & 1;   // A-gen: row am, k-half ag

  f32x4 acc[8][4];
#pragma unroll
  for (int mt = 0; mt < 8; ++mt)
#pragma unroll
    for (int nt = 0; nt < 4; ++nt) { f32x4 z = {0.f, 0.f, 0.f, 0.f}; acc[mt][nt] = z; }

  auto loadWin = [&](int ss) {
    int j0 = (ss & 3) * 32 + ag * 16;
    const uint16_t* r0 = att + ((size_t)(b0 + am) * 9 + i_row) * ATT_ROW + j0;
    const uint16_t* r1 = r0 + ATT_ROW;
    Win w;
    w.a0 = *(const u16x8*)r0; w.a1 = *(const u16x8*)(r0 + 8); w.ae = r0[16];
    w.b0 = *(const u16x8*)r1; w.b1 = *(const u16x8*)(r1 + 8); w.be = r1[16];
    return w;
  };

  auto computeA = [&](const Win& w, int ss, char* Ab) {
    float t0[17], t1[17];
#pragma unroll
    for (int e = 0; e < 8; ++e) {
      t0[e] = bf2f((uint16_t)w.a0[e]); t0[e + 8] = bf2f((uint16_t)w.a1[e]);
      t1[e] = bf2f((uint16_t)w.b0[e]); t1[e + 8] = bf2f((uint16_t)w.b1[e]);
    }
    t0[16] = bf2f(w.ae); t1[16] = bf2f(w.be);
    int o = oh * 32 + (ss >> 2);
    float c0  = conv_b[o];
    float k00 = conv_w[o * 4 + 0], k01 = conv_w[o * 4 + 1];
    float k10 = conv_w[o * 4 + 2], k11 = conv_w[o * 4 + 3];
    uint32_t pk[8];
#pragma unroll
    for (int e2 = 0; e2 < 16; e2 += 2) {
      float v0 = fmaf(k00, t0[e2],     fmaf(k01, t0[e2 + 1], fmaf(k10, t1[e2],     fmaf(k11, t1[e2 + 1], c0))));
      float v1 = fmaf(k00, t0[e2 + 1], fmaf(k01, t0[e2 + 2], fmaf(k10, t1[e2 + 1], fmaf(k11, t1[e2 + 2], c0))));
      v0 = fmaxf(v0, 0.f); v1 = fmaxf(v1, 0.f);
      uint32_t pr;
      asm("v_cvt_pk_bf16_f32 %0, %1, %2" : "=v"(pr) : "v"(v0), "v"(v1));
      pk[e2 >> 1] = pr;
    }
    int base = am * 64 + ag * 32;
    u32x4 wv0; wv0.x = pk[0]; wv0.y = pk[1]; wv0.z = pk[2]; wv0.w = pk[3];
    u32x4 wv1; wv1.x = pk[4]; wv1.y = pk[5]; wv1.z = pk[6]; wv1.w = pk[7];
    *(u32x4*)(Ab + S64s(base))      = wv0;
    *(u32x4*)(Ab + S64s(base + 16)) = wv1;
  };

  auto stageB = [&](int ss, char* Bb) {
    int c = (oh * 32 + (ss >> 2)) * 32 + i_row * 4 + (ss & 3);
    const char* gsrc = (const char*)W1s + (size_t)c * 16384;
#pragma unroll
    for (int it = 0; it < 2; ++it) {
      char* ldsb = Bb + (size_t)(it * 512 + (tid & ~63)) * 16;   // wave-uniform base
      cp16(ldsb, gsrc + (size_t)(it * 512 + tid) * 16);
    }
  };

  auto mfmaStep = [&](const char* Ab, const char* Bb) {
    bf16x8 bfr[4];
#pragma unroll
    for (int nt = 0; nt < 4; ++nt) {
      int n = wn * 64 + nt * 16 + ln15;
      bfr[nt] = *(const bf16x8*)(Bb + S64s(n * 64 + g * 16));
    }
    bf16x8 afr[8];
#pragma unroll
    for (int mt = 0; mt < 8; ++mt) {
      int m = wm * 128 + mt * 16 + ln15;
      afr[mt] = *(const bf16x8*)(Ab + S64s(m * 64 + g * 16));
    }
#pragma unroll
    for (int mt = 0; mt < 8; ++mt)
#pragma unroll
      for (int nt = 0; nt < 4; ++nt)
        acc[mt][nt] = __builtin_amdgcn_mfma_f32_16x16x32_bf16(afr[mt], bfr[nt], acc[mt][nt], 0, 0, 0);
  };

  // prologue
  Win wA = loadWin(0);
  computeA(wA, 0, Abuf);
  stageB(0, Bbuf);
  Win wB = loadWin(1);
  __syncthreads();

#pragma unroll 1
  for (int s2 = 0; s2 < 128; s2 += 2) {
    { // even ss: consume Abuf[0]/Bbuf[0]
      const int ss = s2;
      if (ss + 1 < 128) computeA(wB, ss + 1, Abuf + 16384);
      if (ss + 2 < 128) wA = loadWin(ss + 2);
      if (ss + 1 < 128) stageB(ss + 1, Bbuf + 16384);
      mfmaStep(Abuf, Bbuf);
      __syncthreads();
    }
    { // odd ss: consume Abuf[1]/Bbuf[1]
      const int ss = s2 + 1;
      if (ss + 1 < 128) computeA(wA, ss + 1, Abuf);
      if (ss + 2 < 128) wB = loadWin(ss + 2);
      if (ss + 1 < 128) stageB(ss + 1, Bbuf);
      mfmaStep(Abuf + 16384, Bbuf + 16384);
      __syncthreads();
    }
  }

  // epilogue: split-K accumulate
  const int rbase = b0 + wm * 128 + (lane >> 4) * 4;
  const int cbase = wn * 64 + ln15;
#pragma unroll
  for (int mt = 0; mt < 8; ++mt)
#pragma unroll
    for (int nt = 0; nt < 4; ++nt)
#pragma unroll
      for (int r = 0; r < 4; ++r)
        atomicAdd(out1 + (size_t)(rbase + mt * 16 + r) * 256 + cbase + nt * 16,
                  acc[mt][nt][r]);
}

// ---------- final: bias+relu, fc2, node_feats, fc3 ----------
__global__ __launch_bounds__(512) void k_fin(const float* __restrict__ out1,
    const float* __restrict__ fc1_b, const float* __restrict__ fc2_W,
    const float* __restrict__ fc2_b, const float* __restrict__ fc3_W,
    const float* __restrict__ fc3_b, const int* __restrict__ src,
    const int* __restrict__ dst, const float* __restrict__ h2,
    const float* __restrict__ e2, float* __restrict__ outp) {
  int lane = threadIdx.x & 63, w = threadIdx.x >> 6;
  int b  = blockIdx.x * 8 + w;
  int bu = __builtin_amdgcn_readfirstlane(b);
  f32x4 o4 = ((const f32x4*)(out1 + (size_t)bu * 256))[lane];
  f32x4 bi = ((const f32x4*)fc1_b)[lane];
  float v[4];
#pragma unroll
  for (int r = 0; r < 4; ++r) v[r] = fmaxf(o4[r] + bi[r], 0.f);
  float a24[24];
#pragma unroll
  for (int q = 0; q < 24; ++q) a24[q] = 0.f;
#pragma unroll
  for (int r = 0; r < 4; ++r) {
    const float* wr = fc2_W + (size_t)(lane * 4 + r) * 24;
#pragma unroll
    for (int q = 0; q < 24; ++q) a24[q] = fmaf(v[r], wr[q], a24[q]);
  }
#pragma unroll
  for (int q = 0; q < 24; ++q) {
    float t = a24[q];
    t += __shfl_xor(t, 1);  t += __shfl_xor(t, 2);  t += __shfl_xor(t, 4);
    t += __shfl_xor(t, 8);  t += __shfl_xor(t, 16); t += __shfl_xor(t, 32);
    a24[q] = fmaxf(t + fc2_b[q], 0.f);
  }
  int s = src[bu], d2 = dst[bu];
  float nf[24];
#pragma unroll
  for (int q = 0; q < 8; ++q) {
    float hs = h2[(size_t)s * 8 + q];
    float hd = h2[(size_t)d2 * 8 + q];
    nf[q] = hs; nf[8 + q] = hd; nf[16 + q] = hs + hd + e2[(size_t)bu * 8 + q];
  }
  if (lane == 0) {
#pragma unroll
    for (int c = 0; c < 2; ++c) {
      float r = fc3_b[c];
#pragma unroll
      for (int q = 0; q < 24; ++q) r = fmaf(a24[q], fc3_W[q * 2 + c], r);
#pragma unroll
      for (int q = 0; q < 24; ++q) r = fmaf(nf[q], fc3_W[(24 + q) * 2 + c], r);
      outp[(size_t)bu * 2 + c] = r;
    }
  }
}

// ---------- launch ----------
extern "C" void kernel_launch(void* const* d_in, const int* in_sizes, int n_in,
                              void* d_out, int out_size, void* d_ws, size_t ws_size,
                              hipStream_t stream) {
  const float* X         = (const float*)d_in[0];
  const int*   src       = (const int*)d_in[1];
  const int*   dst       = (const int*)d_in[2];
  const float* node_feat = (const float*)d_in[3];
  const float* edge_feat = (const float*)d_in[4];
  const float* attn_W    = (const float*)d_in[5];
  const float* attn_U    = (const float*)d_in[6];
  const float* attn_V    = (const float*)d_in[7];
  const float* conv_w    = (const float*)d_in[8];
  const float* conv_b    = (const float*)d_in[9];
  const float* gc1_W     = (const float*)d_in[10];
  const float* gc1_b     = (const float*)d_in[11];
  const float* gc2_W     = (const float*)d_in[12];
  const float* gc2_b     = (const float*)d_in[13];
  const float* lin1_W    = (const float*)d_in[14];
  const float* lin1_b    = (const float*)d_in[15];
  const float* lin2_W    = (const float*)d_in[16];
  const float* lin2_b    = (const float*)d_in[17];
  const float* fc1_W     = (const float*)d_in[18];
  const float* fc1_b     = (const float*)d_in[19];
  const float* fc2_W     = (const float*)d_in[20];
  const float* fc2_b     = (const float*)d_in[21];
  const float* fc3_W     = (const float*)d_in[22];
  const float* fc3_b     = (const float*)d_in[23];

  char* ws = (char*)d_ws;
  float*    out1 = (float*)(ws + 0);               // 4096*256*4      = 4,194,304
  float*    agg1 = (float*)(ws + 4194304);         // 2048*128*4      = 1,048,576
  float*    agg2 = (float*)(ws + 5242880);         // 2048*128*4      = 1,048,576
  float*    degO = (float*)(ws + 6291456);         // 2048*4
  float*    degI = (float*)(ws + 6299648);         // 2048*4
  uint16_t* W1s  = (uint16_t*)(ws + 6307840);      // 65536*256*2     = 33,554,432
  uint16_t* att  = (uint16_t*)(ws + 39862272);     // 4096*9*136*2    = 10,027,008
  float*    h1   = (float*)(ws + 49889280);        // 2048*128*4
  float*    h2   = (float*)(ws + 50937856);        // 2048*8*4
  float*    e2   = (float*)(ws + 51003392);        // 4096*8*4

  hipMemsetAsync(d_ws, 0, 6307840, stream);        // out1, agg1, agg2, degs

  k_prep<<<dim3(2048), dim3(256), 0, stream>>>(fc1_W, W1s);
  k_att <<<dim3(256),  dim3(512), 0, stream>>>(X, attn_W, attn_U, attn_V, att);
  k_deg <<<dim3(16),   dim3(256), 0, stream>>>(src, dst, degO, degI);
  k_gca <<<dim3(2048), dim3(256), 0, stream>>>(node_feat, src, dst, degO, agg1);
  k_gc1b<<<dim3(2048), dim3(128), 0, stream>>>(agg1, degI, gc1_W, gc1_b, h1);
  k_gca <<<dim3(2048), dim3(256), 0, stream>>>(h1, src, dst, degO, agg2);
  k_gc2b<<<dim3(2048), dim3(128), 0, stream>>>(agg2, degI, gc2_W, gc2_b, h2);
  k_e12 <<<dim3(256),  dim3(128), 0, stream>>>(edge_feat, lin1_W, lin1_b, lin2_W, lin2_b, e2);
  k_gemm<<<dim3(256),  dim3(512), 0, stream>>>(W1s, att, conv_w, conv_b, out1);
  k_fin <<<dim3(512),  dim3(512), 0, stream>>>(out1, fc1_b, fc2_W, fc2_b, fc3_W, fc3_b,
                                               src, dst, h2, e2, (float*)d_out);
}